// Round 2
// baseline (343.135 us; speedup 1.0000x reference)
//
#include <hip/hip_runtime.h>
#include <math.h>

typedef _Float16 f16;
typedef _Float16 f16x8 __attribute__((ext_vector_type(8)));
typedef _Float16 f16x4 __attribute__((ext_vector_type(4)));
typedef float f32x4 __attribute__((ext_vector_type(4)));

#define N_TOK 2048
#define C_DIM 1024
#define E_NUM 8
#define F_DIM 2048
#define MAXTILES 40  // sum_e ceil(cnt_e/128) <= 4096/128 + 8

// ws layout (bytes)
#define WS_COUNTS    0
#define WS_OFFSETS   64
#define WS_TILESTART 128
#define WS_CURSOR    192
#define WS_TOPI      256
#define WS_TOPW      (WS_TOPI + 16384)
#define WS_ROWS      (WS_TOPW + 16384)
#define WS_SLOT      (WS_ROWS + 16384)
#define WS_H         (1u << 20)
#define WS_Y         (18u << 20)

// ---------------- router: fp32 logits, softmax, top-2 ----------------
__global__ void router_kernel(const float* __restrict__ x, const float* __restrict__ Wr,
                              int* counts, int* topi, float* topw) {
  int tok = blockIdx.x * 4 + (threadIdx.x >> 6);
  int lane = threadIdx.x & 63;
  const float* xr = x + (size_t)tok * C_DIM;
  float xv[16];
#pragma unroll
  for (int i = 0; i < 16; ++i) xv[i] = xr[i * 64 + lane];
  float logit[E_NUM];
#pragma unroll
  for (int e = 0; e < E_NUM; ++e) {
    const float* wr = Wr + (size_t)e * C_DIM;
    float acc = 0.f;
#pragma unroll
    for (int i = 0; i < 16; ++i) acc += xv[i] * wr[i * 64 + lane];
#pragma unroll
    for (int s = 1; s < 64; s <<= 1) acc += __shfl_xor(acc, s, 64);
    logit[e] = acc;
  }
  if (lane == 0) {
    float m = logit[0];
#pragma unroll
    for (int e = 1; e < E_NUM; ++e) m = fmaxf(m, logit[e]);
    float p[E_NUM];
#pragma unroll
    for (int e = 0; e < E_NUM; ++e) p[e] = expf(logit[e] - m);
    float p0 = -1.f, p1 = -1.f;
    int i0 = 0, i1 = 0;
#pragma unroll
    for (int e = 0; e < E_NUM; ++e) {
      float v = p[e];
      if (v > p0) { p1 = p0; i1 = i0; p0 = v; i0 = e; }
      else if (v > p1) { p1 = v; i1 = e; }
    }
    float inv = 1.f / (p0 + p1);
    topi[2 * tok] = i0; topi[2 * tok + 1] = i1;
    topw[2 * tok] = p0 * inv; topw[2 * tok + 1] = p1 * inv;
    atomicAdd(&counts[i0], 1);
    atomicAdd(&counts[i1], 1);
  }
}

// ---------------- scan: offsets, tile starts, cursors ----------------
__global__ void scan_kernel(const int* counts, int* offsets, int* tilestart, int* cursor) {
  if (threadIdx.x == 0) {
    int o = 0, t = 0;
    for (int e = 0; e < E_NUM; ++e) {
      offsets[e] = o; tilestart[e] = t; cursor[e] = o;
      o += counts[e];
      t += (counts[e] + 127) >> 7;
    }
    offsets[E_NUM] = o; tilestart[E_NUM] = t;
  }
}

// ---------------- scatter: build per-expert row lists ----------------
__global__ void scatter_kernel(const int* __restrict__ topi, int* cursor,
                               int* rows_perm, int* slot_of) {
  int n = blockIdx.x * blockDim.x + threadIdx.x;
  if (n >= N_TOK) return;
#pragma unroll
  for (int k = 0; k < 2; ++k) {
    int e = topi[2 * n + k];
    int pos = atomicAdd(&cursor[e], 1);
    rows_perm[pos] = n;
    slot_of[2 * n + k] = pos;
  }
}

// ---------------- up-proj: h = silu(x@w1) * (x@w3), fp16 MFMA ----------------
__launch_bounds__(256)
__global__ void upproj_kernel(const float* __restrict__ x,
                              const float* __restrict__ w1,
                              const float* __restrict__ w3,
                              const int* __restrict__ counts,
                              const int* __restrict__ offsets,
                              const int* __restrict__ tilestart,
                              const int* __restrict__ rows_perm,
                              f16* __restrict__ h_buf) {
  __shared__ f16 A_lds[128][40];
  __shared__ f16 B1_lds[64][40];
  __shared__ f16 B3_lds[64][40];

  int rt = blockIdx.y;
  int e = -1;
#pragma unroll
  for (int i = 0; i < E_NUM; ++i)
    if (rt >= tilestart[i] && rt < tilestart[i + 1]) e = i;
  if (e < 0) return;
  int row0 = (rt - tilestart[e]) * 128;
  int cnt = counts[e];
  int off = offsets[e];
  int f0 = blockIdx.x * 64;
  int t = threadIdx.x;

  int grow[4];
#pragma unroll
  for (int p = 0; p < 4; ++p) {
    int lr = row0 + p * 32 + (t >> 3);
    grow[p] = (lr < cnt) ? rows_perm[off + lr] : -1;
  }

  f32x4 acc1[4][2] = {};
  f32x4 acc3[4][2] = {};
  int wid = t >> 6, lane = t & 63;
  int wr = (wid >> 1) * 64, wc = (wid & 1) * 32;
  int fr = lane & 15, fq = lane >> 4;

  const size_t ebase = (size_t)e * C_DIM * F_DIM;

  for (int k0 = 0; k0 < C_DIM; k0 += 32) {
    __syncthreads();
    // stage A (gathered x rows, fp32 -> fp16)
#pragma unroll
    for (int p = 0; p < 4; ++p) {
      int r = p * 32 + (t >> 3);
      int kq = (t & 7) * 4;
      f32x4 v = {};
      if (grow[p] >= 0) v = *(const f32x4*)(x + (size_t)grow[p] * C_DIM + k0 + kq);
      f16x4 hv;
      hv[0] = (f16)v[0]; hv[1] = (f16)v[1]; hv[2] = (f16)v[2]; hv[3] = (f16)v[3];
      *(f16x4*)&A_lds[r][kq] = hv;
    }
    // stage B1/B3 transposed: B_lds[col][k]
    {
      int kr = t >> 4;
      int cq = (t & 15) * 4;
#pragma unroll
      for (int p = 0; p < 2; ++p) {
        int k = p * 16 + kr;
        f32x4 v1 = *(const f32x4*)(w1 + ebase + (size_t)(k0 + k) * F_DIM + f0 + cq);
        f32x4 v3 = *(const f32x4*)(w3 + ebase + (size_t)(k0 + k) * F_DIM + f0 + cq);
#pragma unroll
        for (int i = 0; i < 4; ++i) {
          B1_lds[cq + i][k] = (f16)v1[i];
          B3_lds[cq + i][k] = (f16)v3[i];
        }
      }
    }
    __syncthreads();
    // one 16x16x32 MFMA consumes the full K=32 tile:
    // per-lane k-offset = (lane>>4)*8, spanning k=0..31 across lane groups
    {
      f16x8 a[4], b1[2], b3[2];
#pragma unroll
      for (int m = 0; m < 4; ++m) a[m] = *(const f16x8*)&A_lds[wr + m * 16 + fr][fq * 8];
#pragma unroll
      for (int n = 0; n < 2; ++n) {
        b1[n] = *(const f16x8*)&B1_lds[wc + n * 16 + fr][fq * 8];
        b3[n] = *(const f16x8*)&B3_lds[wc + n * 16 + fr][fq * 8];
      }
#pragma unroll
      for (int m = 0; m < 4; ++m)
#pragma unroll
        for (int n = 0; n < 2; ++n) {
          acc1[m][n] = __builtin_amdgcn_mfma_f32_16x16x32_f16(a[m], b1[n], acc1[m][n], 0, 0, 0);
          acc3[m][n] = __builtin_amdgcn_mfma_f32_16x16x32_f16(a[m], b3[n], acc3[m][n], 0, 0, 0);
        }
    }
  }
  // epilogue: silu(h1)*h3 -> fp16 h
#pragma unroll
  for (int m = 0; m < 4; ++m)
#pragma unroll
    for (int n = 0; n < 2; ++n)
#pragma unroll
      for (int i = 0; i < 4; ++i) {
        int lr = row0 + wr + m * 16 + fq * 4 + i;
        if (lr < cnt) {
          float v1 = acc1[m][n][i], v3 = acc3[m][n][i];
          float hval = v1 / (1.f + expf(-v1)) * v3;
          h_buf[(size_t)(off + lr) * F_DIM + f0 + wc + n * 16 + fr] = (f16)hval;
        }
      }
}

// ---------------- down-proj: y = h @ w2 ----------------
__launch_bounds__(256)
__global__ void downproj_kernel(const f16* __restrict__ h_buf,
                                const float* __restrict__ w2,
                                const int* __restrict__ counts,
                                const int* __restrict__ offsets,
                                const int* __restrict__ tilestart,
                                float* __restrict__ y_buf) {
  __shared__ f16 A_lds[128][40];
  __shared__ f16 B_lds[64][40];

  int rt = blockIdx.y;
  int e = -1;
#pragma unroll
  for (int i = 0; i < E_NUM; ++i)
    if (rt >= tilestart[i] && rt < tilestart[i + 1]) e = i;
  if (e < 0) return;
  int row0 = (rt - tilestart[e]) * 128;
  int cnt = counts[e];
  int off = offsets[e];
  int c0 = blockIdx.x * 64;
  int t = threadIdx.x;

  f32x4 acc[4][2] = {};
  int wid = t >> 6, lane = t & 63;
  int wr = (wid >> 1) * 64, wc = (wid & 1) * 32;
  int fr = lane & 15, fq = lane >> 4;

  const size_t ebase = (size_t)e * F_DIM * C_DIM;

  for (int k0 = 0; k0 < F_DIM; k0 += 32) {
    __syncthreads();
    // stage A (h rows, already fp16)
#pragma unroll
    for (int p = 0; p < 2; ++p) {
      int r = p * 64 + (t >> 2);
      int k8 = (t & 3) * 8;
      int lr = row0 + r;
      f16x8 v = {};
      if (lr < cnt) v = *(const f16x8*)(h_buf + (size_t)(off + lr) * F_DIM + k0 + k8);
      *(f16x8*)&A_lds[r][k8] = v;
    }
    // stage B transposed
    {
      int kr = t >> 4;
      int cq = (t & 15) * 4;
#pragma unroll
      for (int p = 0; p < 2; ++p) {
        int k = p * 16 + kr;
        f32x4 v = *(const f32x4*)(w2 + ebase + (size_t)(k0 + k) * C_DIM + c0 + cq);
#pragma unroll
        for (int i = 0; i < 4; ++i) B_lds[cq + i][k] = (f16)v[i];
      }
    }
    __syncthreads();
    {
      f16x8 a[4], b[2];
#pragma unroll
      for (int m = 0; m < 4; ++m) a[m] = *(const f16x8*)&A_lds[wr + m * 16 + fr][fq * 8];
#pragma unroll
      for (int n = 0; n < 2; ++n) b[n] = *(const f16x8*)&B_lds[wc + n * 16 + fr][fq * 8];
#pragma unroll
      for (int m = 0; m < 4; ++m)
#pragma unroll
        for (int n = 0; n < 2; ++n)
          acc[m][n] = __builtin_amdgcn_mfma_f32_16x16x32_f16(a[m], b[n], acc[m][n], 0, 0, 0);
    }
  }
#pragma unroll
  for (int m = 0; m < 4; ++m)
#pragma unroll
    for (int n = 0; n < 2; ++n)
#pragma unroll
      for (int i = 0; i < 4; ++i) {
        int lr = row0 + wr + m * 16 + fq * 4 + i;
        if (lr < cnt)
          y_buf[(size_t)(off + lr) * C_DIM + c0 + wc + n * 16 + fr] = acc[m][n][i];
      }
}

// ---------------- combine: out[n] = g0*y[s0] + g1*y[s1] ----------------
__global__ void combine_kernel(const float* __restrict__ y_buf,
                               const int* __restrict__ slot_of,
                               const float* __restrict__ topw,
                               float* __restrict__ out) {
  int n = blockIdx.x;
  int s0 = slot_of[2 * n], s1 = slot_of[2 * n + 1];
  float g0 = topw[2 * n], g1 = topw[2 * n + 1];
  int c = threadIdx.x * 4;
  f32x4 a = *(const f32x4*)(y_buf + (size_t)s0 * C_DIM + c);
  f32x4 b = *(const f32x4*)(y_buf + (size_t)s1 * C_DIM + c);
  f32x4 o;
#pragma unroll
  for (int i = 0; i < 4; ++i) o[i] = g0 * a[i] + g1 * b[i];
  *(f32x4*)(out + (size_t)n * C_DIM + c) = o;
}

extern "C" void kernel_launch(void* const* d_in, const int* in_sizes, int n_in,
                              void* d_out, int out_size, void* d_ws, size_t ws_size,
                              hipStream_t stream) {
  const float* x  = (const float*)d_in[0];
  const float* Wr = (const float*)d_in[1];
  const float* w1 = (const float*)d_in[2];
  const float* w3 = (const float*)d_in[3];
  const float* w2 = (const float*)d_in[4];
  float* out = (float*)d_out;
  char* ws = (char*)d_ws;

  int* counts    = (int*)(ws + WS_COUNTS);
  int* offsets   = (int*)(ws + WS_OFFSETS);
  int* tilestart = (int*)(ws + WS_TILESTART);
  int* cursor    = (int*)(ws + WS_CURSOR);
  int* topi      = (int*)(ws + WS_TOPI);
  float* topw    = (float*)(ws + WS_TOPW);
  int* rows_perm = (int*)(ws + WS_ROWS);
  int* slot_of   = (int*)(ws + WS_SLOT);
  f16* h_buf     = (f16*)(ws + WS_H);
  float* y_buf   = (float*)(ws + WS_Y);

  hipMemsetAsync(ws, 0, 256, stream);
  router_kernel<<<N_TOK / 4, 256, 0, stream>>>(x, Wr, counts, topi, topw);
  scan_kernel<<<1, 64, 0, stream>>>(counts, offsets, tilestart, cursor);
  scatter_kernel<<<N_TOK / 256, 256, 0, stream>>>(topi, cursor, rows_perm, slot_of);
  upproj_kernel<<<dim3(F_DIM / 64, MAXTILES), 256, 0, stream>>>(
      x, w1, w3, counts, offsets, tilestart, rows_perm, h_buf);
  downproj_kernel<<<dim3(C_DIM / 64, MAXTILES), 256, 0, stream>>>(
      h_buf, w2, counts, offsets, tilestart, y_buf);
  combine_kernel<<<N_TOK, 256, 0, stream>>>(y_buf, slot_of, topw, out);
}

// Round 4
// 244.112 us; speedup vs baseline: 1.4056x; 1.4056x over previous
//
#include <hip/hip_runtime.h>
#include <math.h>

typedef _Float16 f16;
typedef _Float16 f16x2 __attribute__((ext_vector_type(2)));
typedef _Float16 f16x4 __attribute__((ext_vector_type(4)));
typedef _Float16 f16x8 __attribute__((ext_vector_type(8)));
typedef __fp16 h16x2 __attribute__((ext_vector_type(2)));
typedef float f32x4 __attribute__((ext_vector_type(4)));

#define N_TOK 2048
#define C_DIM 1024
#define E_NUM 8
#define F_DIM 2048
#define MAXTILES 40  // sum_e ceil(cnt_e/128) <= 4096/128 + 8

// ws layout (bytes)
#define WS_COUNTS    0
#define WS_OFFSETS   64
#define WS_TILESTART 128
#define WS_CURSOR    192
#define WS_TOPI      256
#define WS_TOPW      (WS_TOPI + 16384)
#define WS_ROWS      (WS_TOPW + 16384)
#define WS_SLOT      (WS_ROWS + 16384)
#define WS_X16       (1u << 20)    // 4 MB   (2048x1024 f16)
#define WS_H         (6u << 20)    // 16.8 MB (4096x2048 f16)
#define WS_Y0        (23u << 20)   // 8.4 MB (4096x1024 f16)
#define WS_Y1        (32u << 20)   // 8.4 MB

__device__ __forceinline__ void glds16(const void* g, void* l) {
  __builtin_amdgcn_global_load_lds((const __attribute__((address_space(1))) void*)g,
                                   (__attribute__((address_space(3))) void*)l, 16, 0, 0);
}

__device__ __forceinline__ f16x2 pkrtz(float a, float b) {
  union { h16x2 h; f16x2 f; } u;
  u.h = __builtin_amdgcn_cvt_pkrtz(a, b);
  return u.f;
}

// ---------------- x fp32 -> fp16 ----------------
__global__ void cvtx_kernel(const float* __restrict__ x, f16* __restrict__ x16) {
  int i = (blockIdx.x * 256 + threadIdx.x) * 8;
  f32x4 a = *(const f32x4*)(x + i);
  f32x4 b = *(const f32x4*)(x + i + 4);
  union { f16x8 v; f16x2 h[4]; } u;
  u.h[0] = pkrtz(a[0], a[1]);
  u.h[1] = pkrtz(a[2], a[3]);
  u.h[2] = pkrtz(b[0], b[1]);
  u.h[3] = pkrtz(b[2], b[3]);
  *(f16x8*)(x16 + i) = u.v;
}

// ---------------- router: fp32 logits, softmax, top-2 ----------------
__global__ void router_kernel(const float* __restrict__ x, const float* __restrict__ Wr,
                              int* counts, int* topi, float* topw) {
  int tok = blockIdx.x * 4 + (threadIdx.x >> 6);
  int lane = threadIdx.x & 63;
  const float* xr = x + (size_t)tok * C_DIM;
  float xv[16];
#pragma unroll
  for (int i = 0; i < 16; ++i) xv[i] = xr[i * 64 + lane];
  float logit[E_NUM];
#pragma unroll
  for (int e = 0; e < E_NUM; ++e) {
    const float* wr = Wr + (size_t)e * C_DIM;
    float acc = 0.f;
#pragma unroll
    for (int i = 0; i < 16; ++i) acc += xv[i] * wr[i * 64 + lane];
#pragma unroll
    for (int s = 1; s < 64; s <<= 1) acc += __shfl_xor(acc, s, 64);
    logit[e] = acc;
  }
  if (lane == 0) {
    float m = logit[0];
#pragma unroll
    for (int e = 1; e < E_NUM; ++e) m = fmaxf(m, logit[e]);
    float p[E_NUM];
#pragma unroll
    for (int e = 0; e < E_NUM; ++e) p[e] = expf(logit[e] - m);
    float p0 = -1.f, p1 = -1.f;
    int i0 = 0, i1 = 0;
#pragma unroll
    for (int e = 0; e < E_NUM; ++e) {
      float v = p[e];
      if (v > p0) { p1 = p0; i1 = i0; p0 = v; i0 = e; }
      else if (v > p1) { p1 = v; i1 = e; }
    }
    float inv = 1.f / (p0 + p1);
    topi[2 * tok] = i0; topi[2 * tok + 1] = i1;
    topw[2 * tok] = p0 * inv; topw[2 * tok + 1] = p1 * inv;
    atomicAdd(&counts[i0], 1);
    atomicAdd(&counts[i1], 1);
  }
}

// ---------------- scan ----------------
__global__ void scan_kernel(const int* counts, int* offsets, int* tilestart, int* cursor) {
  if (threadIdx.x == 0) {
    int o = 0, t = 0;
    for (int e = 0; e < E_NUM; ++e) {
      offsets[e] = o; tilestart[e] = t; cursor[e] = o;
      o += counts[e];
      t += (counts[e] + 127) >> 7;
    }
    offsets[E_NUM] = o; tilestart[E_NUM] = t;
  }
}

// ---------------- scatter ----------------
__global__ void scatter_kernel(const int* __restrict__ topi, int* cursor,
                               int* rows_perm, int* slot_of) {
  int n = blockIdx.x * blockDim.x + threadIdx.x;
  if (n >= N_TOK) return;
#pragma unroll
  for (int k = 0; k < 2; ++k) {
    int e = topi[2 * n + k];
    int pos = atomicAdd(&cursor[e], 1);
    rows_perm[pos] = n;
    slot_of[2 * n + k] = pos;
  }
}

// ---------------- up-proj: h = silu(x@w1)*(x@w3) ----------------
// Tile: 128 rows x 128 f-cols, BK=32, 4 waves each 64x64.
// A: glds from x16 (gathered rows), cell-swizzled: logical k-cell kc (8 f16)
//    of row r stored at cell kc ^ ((r>>1)&3). B: [col][k] f16 same swizzle.
__launch_bounds__(256, 2)
__global__ void upproj_kernel(const f16* __restrict__ x16,
                              const float* __restrict__ w1,
                              const float* __restrict__ w3,
                              const int* __restrict__ counts,
                              const int* __restrict__ offsets,
                              const int* __restrict__ tilestart,
                              const int* __restrict__ rows_perm,
                              f16* __restrict__ h_buf) {
  __shared__ f16 A_lds[128 * 32];
  __shared__ f16 B1_lds[128 * 32];
  __shared__ f16 B3_lds[128 * 32];

  int rt = blockIdx.y;
  int e = -1;
#pragma unroll
  for (int i = 0; i < E_NUM; ++i)
    if (rt >= tilestart[i] && rt < tilestart[i + 1]) e = i;
  if (e < 0) return;
  int row0 = (rt - tilestart[e]) * 128;
  int cnt = counts[e];
  int off = offsets[e];
  int f0 = blockIdx.x * 128;
  int t = threadIdx.x, wid = t >> 6, lane = t & 63;

  // A glds: 512 chunks of 16B; chunk = p*256+t -> (row, destcell)
  const f16* asrc[2];
#pragma unroll
  for (int p = 0; p < 2; ++p) {
    int chunk = p * 256 + t, row = chunk >> 2, cc = chunk & 3;
    int lr = row0 + row; if (lr > cnt - 1) lr = cnt - 1;
    int g = rows_perm[off + lr];
    asrc[p] = x16 + (size_t)g * C_DIM + 8 * (cc ^ ((row >> 1) & 3));
  }
  f16* adst0 = A_lds + wid * 512;        // (p*4+wid)*1024 bytes
  f16* adst1 = A_lds + (4 + wid) * 512;

  // B staging: col = t&127, k-range bg*16..+15
  int bcol = t & 127;
  int bg = t >> 7;
  int bxor = (bcol >> 1) & 3;
  const size_t eb = (size_t)e * C_DIM * F_DIM;
  const float* w1p = w1 + eb + (size_t)(bg * 16) * F_DIM + f0 + bcol;
  const float* w3p = w3 + eb + (size_t)(bg * 16) * F_DIM + f0 + bcol;

  f32x4 acc1[4][4] = {};
  f32x4 acc3[4][4] = {};
  int wr = (wid >> 1) * 64, wc = (wid & 1) * 64;
  int fr = lane & 15, fq = lane >> 4;

  for (int k0 = 0; k0 < C_DIM; k0 += 32) {
    __syncthreads();
    glds16(asrc[0] + k0, adst0);
    glds16(asrc[1] + k0, adst1);
    {
      float v[16];
#pragma unroll
      for (int j = 0; j < 16; ++j) v[j] = w1p[(size_t)(k0 + j) * F_DIM];
#pragma unroll
      for (int q = 0; q < 4; ++q) {
        union { f16x4 v4; f16x2 h2[2]; } u;
        u.h2[0] = pkrtz(v[q * 4 + 0], v[q * 4 + 1]);
        u.h2[1] = pkrtz(v[q * 4 + 2], v[q * 4 + 3]);
        int k = bg * 16 + q * 4;
        *(f16x4*)&B1_lds[bcol * 32 + ((k >> 3) ^ bxor) * 8 + (k & 7)] = u.v4;
      }
#pragma unroll
      for (int j = 0; j < 16; ++j) v[j] = w3p[(size_t)(k0 + j) * F_DIM];
#pragma unroll
      for (int q = 0; q < 4; ++q) {
        union { f16x4 v4; f16x2 h2[2]; } u;
        u.h2[0] = pkrtz(v[q * 4 + 0], v[q * 4 + 1]);
        u.h2[1] = pkrtz(v[q * 4 + 2], v[q * 4 + 3]);
        int k = bg * 16 + q * 4;
        *(f16x4*)&B3_lds[bcol * 32 + ((k >> 3) ^ bxor) * 8 + (k & 7)] = u.v4;
      }
    }
    __syncthreads();

    f16x8 a[4];
#pragma unroll
    for (int m = 0; m < 4; ++m) {
      int row = wr + m * 16 + fr;
      a[m] = *(const f16x8*)&A_lds[row * 32 + (fq ^ ((row >> 1) & 3)) * 8];
    }
    f16x8 b[4];
#pragma unroll
    for (int n = 0; n < 4; ++n) {
      int col = wc + n * 16 + fr;
      b[n] = *(const f16x8*)&B1_lds[col * 32 + (fq ^ ((col >> 1) & 3)) * 8];
    }
#pragma unroll
    for (int m = 0; m < 4; ++m)
#pragma unroll
      for (int n = 0; n < 4; ++n)
        acc1[m][n] = __builtin_amdgcn_mfma_f32_16x16x32_f16(a[m], b[n], acc1[m][n], 0, 0, 0);
#pragma unroll
    for (int n = 0; n < 4; ++n) {
      int col = wc + n * 16 + fr;
      b[n] = *(const f16x8*)&B3_lds[col * 32 + (fq ^ ((col >> 1) & 3)) * 8];
    }
#pragma unroll
    for (int m = 0; m < 4; ++m)
#pragma unroll
      for (int n = 0; n < 4; ++n)
        acc3[m][n] = __builtin_amdgcn_mfma_f32_16x16x32_f16(a[m], b[n], acc3[m][n], 0, 0, 0);
  }

#pragma unroll
  for (int m = 0; m < 4; ++m)
#pragma unroll
    for (int n = 0; n < 4; ++n)
#pragma unroll
      for (int i = 0; i < 4; ++i) {
        int lr = row0 + wr + m * 16 + fq * 4 + i;
        if (lr < cnt) {
          float v1 = acc1[m][n][i], v3 = acc3[m][n][i];
          float hval = v1 / (1.f + expf(-v1)) * v3;
          h_buf[(size_t)(off + lr) * F_DIM + f0 + wc + n * 16 + fr] = (f16)hval;
        }
      }
}

// ---------------- down-proj: y_kh = h[:, kh*1024:+1024] @ w2[kh*1024:+1024, :] ----------------
__launch_bounds__(256, 2)
__global__ void downproj_kernel(const f16* __restrict__ h_buf,
                                const float* __restrict__ w2,
                                const int* __restrict__ counts,
                                const int* __restrict__ offsets,
                                const int* __restrict__ tilestart,
                                f16* __restrict__ y0,
                                f16* __restrict__ y1) {
  __shared__ f16 A_lds[128 * 32];
  __shared__ f16 B_lds[128 * 32];

  int kh = blockIdx.z;
  f16* yb = kh ? y1 : y0;
  int rt = blockIdx.y;
  int e = -1;
#pragma unroll
  for (int i = 0; i < E_NUM; ++i)
    if (rt >= tilestart[i] && rt < tilestart[i + 1]) e = i;
  if (e < 0) return;
  int row0 = (rt - tilestart[e]) * 128;
  int cnt = counts[e];
  int off = offsets[e];
  int c0 = blockIdx.x * 128;
  int t = threadIdx.x, wid = t >> 6, lane = t & 63;

  const f16* asrc[2];
#pragma unroll
  for (int p = 0; p < 2; ++p) {
    int chunk = p * 256 + t, row = chunk >> 2, cc = chunk & 3;
    int lr = row0 + row; if (lr > cnt - 1) lr = cnt - 1;
    asrc[p] = h_buf + (size_t)(off + lr) * F_DIM + kh * 1024 + 8 * (cc ^ ((row >> 1) & 3));
  }
  f16* adst0 = A_lds + wid * 512;
  f16* adst1 = A_lds + (4 + wid) * 512;

  int bcol = t & 127;
  int bg = t >> 7;
  int bxor = (bcol >> 1) & 3;
  const float* w2p = w2 + (size_t)e * F_DIM * C_DIM
                     + (size_t)(kh * 1024 + bg * 16) * C_DIM + c0 + bcol;

  f32x4 acc[4][4] = {};
  int wr = (wid >> 1) * 64, wc = (wid & 1) * 64;
  int fr = lane & 15, fq = lane >> 4;

  for (int k0 = 0; k0 < 1024; k0 += 32) {
    __syncthreads();
    glds16(asrc[0] + k0, adst0);
    glds16(asrc[1] + k0, adst1);
    {
      float v[16];
#pragma unroll
      for (int j = 0; j < 16; ++j) v[j] = w2p[(size_t)(k0 + j) * C_DIM];
#pragma unroll
      for (int q = 0; q < 4; ++q) {
        union { f16x4 v4; f16x2 h2[2]; } u;
        u.h2[0] = pkrtz(v[q * 4 + 0], v[q * 4 + 1]);
        u.h2[1] = pkrtz(v[q * 4 + 2], v[q * 4 + 3]);
        int k = bg * 16 + q * 4;
        *(f16x4*)&B_lds[bcol * 32 + ((k >> 3) ^ bxor) * 8 + (k & 7)] = u.v4;
      }
    }
    __syncthreads();

    f16x8 a[4];
#pragma unroll
    for (int m = 0; m < 4; ++m) {
      int row = wr + m * 16 + fr;
      a[m] = *(const f16x8*)&A_lds[row * 32 + (fq ^ ((row >> 1) & 3)) * 8];
    }
    f16x8 b[4];
#pragma unroll
    for (int n = 0; n < 4; ++n) {
      int col = wc + n * 16 + fr;
      b[n] = *(const f16x8*)&B_lds[col * 32 + (fq ^ ((col >> 1) & 3)) * 8];
    }
#pragma unroll
    for (int m = 0; m < 4; ++m)
#pragma unroll
      for (int n = 0; n < 4; ++n)
        acc[m][n] = __builtin_amdgcn_mfma_f32_16x16x32_f16(a[m], b[n], acc[m][n], 0, 0, 0);
  }

#pragma unroll
  for (int m = 0; m < 4; ++m)
#pragma unroll
    for (int n = 0; n < 4; ++n)
#pragma unroll
      for (int i = 0; i < 4; ++i) {
        int lr = row0 + wr + m * 16 + fq * 4 + i;
        if (lr < cnt)
          yb[(size_t)(off + lr) * C_DIM + c0 + wc + n * 16 + fr] = (f16)acc[m][n][i];
      }
}

// ---------------- combine ----------------
__global__ void combine_kernel(const f16* __restrict__ y0, const f16* __restrict__ y1,
                               const int* __restrict__ slot_of,
                               const float* __restrict__ topw,
                               float* __restrict__ out) {
  int n = blockIdx.x;
  int s0 = slot_of[2 * n], s1 = slot_of[2 * n + 1];
  float g0 = topw[2 * n], g1 = topw[2 * n + 1];
  int c = threadIdx.x * 4;
  f16x4 a0 = *(const f16x4*)(y0 + (size_t)s0 * C_DIM + c);
  f16x4 a1 = *(const f16x4*)(y1 + (size_t)s0 * C_DIM + c);
  f16x4 b0 = *(const f16x4*)(y0 + (size_t)s1 * C_DIM + c);
  f16x4 b1 = *(const f16x4*)(y1 + (size_t)s1 * C_DIM + c);
  f32x4 o;
#pragma unroll
  for (int i = 0; i < 4; ++i)
    o[i] = g0 * ((float)a0[i] + (float)a1[i]) + g1 * ((float)b0[i] + (float)b1[i]);
  *(f32x4*)(out + (size_t)n * C_DIM + c) = o;
}

extern "C" void kernel_launch(void* const* d_in, const int* in_sizes, int n_in,
                              void* d_out, int out_size, void* d_ws, size_t ws_size,
                              hipStream_t stream) {
  const float* x  = (const float*)d_in[0];
  const float* Wr = (const float*)d_in[1];
  const float* w1 = (const float*)d_in[2];
  const float* w3 = (const float*)d_in[3];
  const float* w2 = (const float*)d_in[4];
  float* out = (float*)d_out;
  char* ws = (char*)d_ws;

  int* counts    = (int*)(ws + WS_COUNTS);
  int* offsets   = (int*)(ws + WS_OFFSETS);
  int* tilestart = (int*)(ws + WS_TILESTART);
  int* cursor    = (int*)(ws + WS_CURSOR);
  int* topi      = (int*)(ws + WS_TOPI);
  float* topw    = (float*)(ws + WS_TOPW);
  int* rows_perm = (int*)(ws + WS_ROWS);
  int* slot_of   = (int*)(ws + WS_SLOT);
  f16* x16       = (f16*)(ws + WS_X16);
  f16* h_buf     = (f16*)(ws + WS_H);
  f16* y0        = (f16*)(ws + WS_Y0);
  f16* y1        = (f16*)(ws + WS_Y1);

  (void)hipMemsetAsync(ws, 0, 256, stream);
  cvtx_kernel<<<N_TOK * C_DIM / 8 / 256, 256, 0, stream>>>(x, x16);
  router_kernel<<<N_TOK / 4, 256, 0, stream>>>(x, Wr, counts, topi, topw);
  scan_kernel<<<1, 64, 0, stream>>>(counts, offsets, tilestart, cursor);
  scatter_kernel<<<N_TOK / 256, 256, 0, stream>>>(topi, cursor, rows_perm, slot_of);
  upproj_kernel<<<dim3(F_DIM / 128, MAXTILES), 256, 0, stream>>>(
      x16, w1, w3, counts, offsets, tilestart, rows_perm, h_buf);
  downproj_kernel<<<dim3(C_DIM / 128, MAXTILES, 2), 256, 0, stream>>>(
      h_buf, w2, counts, offsets, tilestart, y0, y1);
  combine_kernel<<<N_TOK, 256, 0, stream>>>(y0, y1, slot_of, topw, out);
}

// Round 5
// 214.958 us; speedup vs baseline: 1.5963x; 1.1356x over previous
//
#include <hip/hip_runtime.h>
#include <math.h>

typedef _Float16 f16;
typedef _Float16 f16x2 __attribute__((ext_vector_type(2)));
typedef _Float16 f16x4 __attribute__((ext_vector_type(4)));
typedef _Float16 f16x8 __attribute__((ext_vector_type(8)));
typedef __fp16 h16x2 __attribute__((ext_vector_type(2)));
typedef float f32x4 __attribute__((ext_vector_type(4)));

#define N_TOK 2048
#define C_DIM 1024
#define E_NUM 8
#define F_DIM 2048
#define BM 256
#define MAXT2 24   // sum_e ceil(cnt_e/256) <= 4096/256 + 7 < 24

// ws layout (bytes)
#define WS_COUNTS    0
#define WS_OFFSETS   64
#define WS_TILESTART 128
#define WS_CURSOR    192
#define WS_TOPI      256
#define WS_TOPW      (WS_TOPI + 16384)
#define WS_ROWS      (WS_TOPW + 16384)
#define WS_SLOT      (WS_ROWS + 16384)
#define WS_X16       (1u << 20)    // 4 MB   (2048x1024 f16)
#define WS_H         (6u << 20)    // 16.8 MB (4096x2048 f16)
#define WS_Y0        (23u << 20)   // 8.4 MB (4096x1024 f16)
#define WS_Y1        (32u << 20)   // 8.4 MB

__device__ __forceinline__ void glds16(const void* g, void* l) {
  __builtin_amdgcn_global_load_lds((const __attribute__((address_space(1))) void*)g,
                                   (__attribute__((address_space(3))) void*)l, 16, 0, 0);
}

__device__ __forceinline__ f16x2 pkrtz(float a, float b) {
  union { h16x2 h; f16x2 f; } u;
  u.h = __builtin_amdgcn_cvt_pkrtz(a, b);
  return u.f;
}

// ---------------- x fp32 -> fp16 ----------------
__global__ void cvtx_kernel(const float* __restrict__ x, f16* __restrict__ x16) {
  int i = (blockIdx.x * 256 + threadIdx.x) * 8;
  f32x4 a = *(const f32x4*)(x + i);
  f32x4 b = *(const f32x4*)(x + i + 4);
  union { f16x8 v; f16x2 h[4]; } u;
  u.h[0] = pkrtz(a[0], a[1]);
  u.h[1] = pkrtz(a[2], a[3]);
  u.h[2] = pkrtz(b[0], b[1]);
  u.h[3] = pkrtz(b[2], b[3]);
  *(f16x8*)(x16 + i) = u.v;
}

// ---------------- router: fp32 logits, softmax, top-2 ----------------
__global__ void router_kernel(const float* __restrict__ x, const float* __restrict__ Wr,
                              int* counts, int* topi, float* topw) {
  int tok = blockIdx.x * 4 + (threadIdx.x >> 6);
  int lane = threadIdx.x & 63;
  const float* xr = x + (size_t)tok * C_DIM;
  float xv[16];
#pragma unroll
  for (int i = 0; i < 16; ++i) xv[i] = xr[i * 64 + lane];
  float logit[E_NUM];
#pragma unroll
  for (int e = 0; e < E_NUM; ++e) {
    const float* wr = Wr + (size_t)e * C_DIM;
    float acc = 0.f;
#pragma unroll
    for (int i = 0; i < 16; ++i) acc += xv[i] * wr[i * 64 + lane];
#pragma unroll
    for (int s = 1; s < 64; s <<= 1) acc += __shfl_xor(acc, s, 64);
    logit[e] = acc;
  }
  if (lane == 0) {
    float m = logit[0];
#pragma unroll
    for (int e = 1; e < E_NUM; ++e) m = fmaxf(m, logit[e]);
    float p[E_NUM];
#pragma unroll
    for (int e = 0; e < E_NUM; ++e) p[e] = expf(logit[e] - m);
    float p0 = -1.f, p1 = -1.f;
    int i0 = 0, i1 = 0;
#pragma unroll
    for (int e = 0; e < E_NUM; ++e) {
      float v = p[e];
      if (v > p0) { p1 = p0; i1 = i0; p0 = v; i0 = e; }
      else if (v > p1) { p1 = v; i1 = e; }
    }
    float inv = 1.f / (p0 + p1);
    topi[2 * tok] = i0; topi[2 * tok + 1] = i1;
    topw[2 * tok] = p0 * inv; topw[2 * tok + 1] = p1 * inv;
    atomicAdd(&counts[i0], 1);
    atomicAdd(&counts[i1], 1);
  }
}

// ---------------- scan (256-row tiles) ----------------
__global__ void scan_kernel(const int* counts, int* offsets, int* tilestart, int* cursor) {
  if (threadIdx.x == 0) {
    int o = 0, t = 0;
    for (int e = 0; e < E_NUM; ++e) {
      offsets[e] = o; tilestart[e] = t; cursor[e] = o;
      o += counts[e];
      t += (counts[e] + 255) >> 8;
    }
    offsets[E_NUM] = o; tilestart[E_NUM] = t;
  }
}

// ---------------- scatter ----------------
__global__ void scatter_kernel(const int* __restrict__ topi, int* cursor,
                               int* rows_perm, int* slot_of) {
  int n = blockIdx.x * blockDim.x + threadIdx.x;
  if (n >= N_TOK) return;
#pragma unroll
  for (int k = 0; k < 2; ++k) {
    int e = topi[2 * n + k];
    int pos = atomicAdd(&cursor[e], 1);
    rows_perm[pos] = n;
    slot_of[2 * n + k] = pos;
  }
}

// ---------------- up-proj: h = silu(x@w1)*(x@w3) ----------------
// 256x128 tile, BK=32, 8 waves each 64x64 (dual acc). Double-buffered LDS,
// single barrier per K-step; loads for t+1 issued under MFMA of t.
__launch_bounds__(512, 2)
__global__ void upproj_kernel(const f16* __restrict__ x16,
                              const float* __restrict__ w1,
                              const float* __restrict__ w3,
                              const int* __restrict__ counts,
                              const int* __restrict__ offsets,
                              const int* __restrict__ tilestart,
                              const int* __restrict__ rows_perm,
                              f16* __restrict__ h_buf) {
  __shared__ f16 A_lds[2][BM * 32];
  __shared__ f16 B1_lds[2][128 * 32];
  __shared__ f16 B3_lds[2][128 * 32];

  int rt = blockIdx.y;
  int e = -1;
#pragma unroll
  for (int i = 0; i < E_NUM; ++i)
    if (rt >= tilestart[i] && rt < tilestart[i + 1]) e = i;
  if (e < 0) return;
  int row0 = (rt - tilestart[e]) * BM;
  int cnt = counts[e], off = offsets[e];
  int f0 = blockIdx.x * 128;
  int t = threadIdx.x, wid = t >> 6, lane = t & 63;

  // A sources: chunk c = (p*8+wid)*64 + lane ; row = c>>2, destcell = c&3
  const f16* asrc[2];
#pragma unroll
  for (int p = 0; p < 2; ++p) {
    int c = (p * 8 + wid) * 64 + lane;
    int row = c >> 2, cc = c & 3;
    int lr = row0 + row; if (lr > cnt - 1) lr = cnt - 1;
    int g = rows_perm[off + lr];
    asrc[p] = x16 + (size_t)g * C_DIM + 8 * (cc ^ ((row >> 1) & 3));
  }

  int bcol = t & 127, kg = t >> 7;  // col 0..127, k-cell 0..3
  int bso = bcol * 32 + (kg ^ ((bcol >> 1) & 3)) * 8;
  const size_t eb = (size_t)e * C_DIM * F_DIM;
  const float* w1p = w1 + eb + (size_t)(kg * 8) * F_DIM + f0 + bcol;
  const float* w3p = w3 + eb + (size_t)(kg * 8) * F_DIM + f0 + bcol;

  f32x4 acc1[4][4] = {};
  f32x4 acc3[4][4] = {};
  int wr = (wid >> 1) * 64, wc = (wid & 1) * 64;
  int fr = lane & 15, fq = lane >> 4;

  // prologue: tile 0 in flight
  float r1[8], r3[8];
#pragma unroll
  for (int j = 0; j < 8; ++j) {
    r1[j] = w1p[(size_t)j * F_DIM];
    r3[j] = w3p[(size_t)j * F_DIM];
  }
  glds16(asrc[0], &A_lds[0][wid * 512]);
  glds16(asrc[1], &A_lds[0][(8 + wid) * 512]);

#pragma unroll 2
  for (int tt = 0; tt < 32; ++tt) {
    int cur = tt & 1;
    {
      union { f16x8 v; f16x2 h[4]; } u;
      u.h[0] = pkrtz(r1[0], r1[1]); u.h[1] = pkrtz(r1[2], r1[3]);
      u.h[2] = pkrtz(r1[4], r1[5]); u.h[3] = pkrtz(r1[6], r1[7]);
      *(f16x8*)&B1_lds[cur][bso] = u.v;
      u.h[0] = pkrtz(r3[0], r3[1]); u.h[1] = pkrtz(r3[2], r3[3]);
      u.h[2] = pkrtz(r3[4], r3[5]); u.h[3] = pkrtz(r3[6], r3[7]);
      *(f16x8*)&B3_lds[cur][bso] = u.v;
    }
    __syncthreads();   // A[tt] glds drained; everyone past reads of buf cur^1
    int knext = ((tt + 1) & 31) * 32;
    glds16(asrc[0] + knext, &A_lds[cur ^ 1][wid * 512]);
    glds16(asrc[1] + knext, &A_lds[cur ^ 1][(8 + wid) * 512]);
#pragma unroll
    for (int j = 0; j < 8; ++j) {
      r1[j] = w1p[(size_t)(knext + j) * F_DIM];
      r3[j] = w3p[(size_t)(knext + j) * F_DIM];
    }
    f16x8 a[4];
#pragma unroll
    for (int m = 0; m < 4; ++m) {
      int row = wr + m * 16 + fr;
      a[m] = *(const f16x8*)&A_lds[cur][row * 32 + (fq ^ ((row >> 1) & 3)) * 8];
    }
    f16x8 b[4];
#pragma unroll
    for (int n = 0; n < 4; ++n) {
      int col = wc + n * 16 + fr;
      b[n] = *(const f16x8*)&B1_lds[cur][col * 32 + (fq ^ ((col >> 1) & 3)) * 8];
    }
#pragma unroll
    for (int m = 0; m < 4; ++m)
#pragma unroll
      for (int n = 0; n < 4; ++n)
        acc1[m][n] = __builtin_amdgcn_mfma_f32_16x16x32_f16(a[m], b[n], acc1[m][n], 0, 0, 0);
#pragma unroll
    for (int n = 0; n < 4; ++n) {
      int col = wc + n * 16 + fr;
      b[n] = *(const f16x8*)&B3_lds[cur][col * 32 + (fq ^ ((col >> 1) & 3)) * 8];
    }
#pragma unroll
    for (int m = 0; m < 4; ++m)
#pragma unroll
      for (int n = 0; n < 4; ++n)
        acc3[m][n] = __builtin_amdgcn_mfma_f32_16x16x32_f16(a[m], b[n], acc3[m][n], 0, 0, 0);
  }

#pragma unroll
  for (int m = 0; m < 4; ++m)
#pragma unroll
    for (int n = 0; n < 4; ++n)
#pragma unroll
      for (int i = 0; i < 4; ++i) {
        int lr = row0 + wr + m * 16 + fq * 4 + i;
        if (lr < cnt) {
          float v1 = acc1[m][n][i], v3 = acc3[m][n][i];
          float hval = v1 / (1.f + expf(-v1)) * v3;
          h_buf[(size_t)(off + lr) * F_DIM + f0 + wc + n * 16 + fr] = (f16)hval;
        }
      }
}

// ---------------- down-proj: y_kh = h[:, kh*1024:+1024] @ w2[kh*1024:+1024, :] ----------------
__launch_bounds__(512, 2)
__global__ void downproj_kernel(const f16* __restrict__ h_buf,
                                const float* __restrict__ w2,
                                const int* __restrict__ counts,
                                const int* __restrict__ offsets,
                                const int* __restrict__ tilestart,
                                f16* __restrict__ y0,
                                f16* __restrict__ y1) {
  __shared__ f16 A_lds[2][BM * 32];
  __shared__ f16 B_lds[2][128 * 32];

  int kh = blockIdx.z;
  f16* yb = kh ? y1 : y0;
  int rt = blockIdx.y;
  int e = -1;
#pragma unroll
  for (int i = 0; i < E_NUM; ++i)
    if (rt >= tilestart[i] && rt < tilestart[i + 1]) e = i;
  if (e < 0) return;
  int row0 = (rt - tilestart[e]) * BM;
  int cnt = counts[e], off = offsets[e];
  int c0 = blockIdx.x * 128;
  int t = threadIdx.x, wid = t >> 6, lane = t & 63;

  const f16* asrc[2];
#pragma unroll
  for (int p = 0; p < 2; ++p) {
    int c = (p * 8 + wid) * 64 + lane;
    int row = c >> 2, cc = c & 3;
    int lr = row0 + row; if (lr > cnt - 1) lr = cnt - 1;
    asrc[p] = h_buf + (size_t)(off + lr) * F_DIM + kh * 1024 + 8 * (cc ^ ((row >> 1) & 3));
  }

  int bcol = t & 127, kg = t >> 7;
  int bso = bcol * 32 + (kg ^ ((bcol >> 1) & 3)) * 8;
  const float* w2p = w2 + (size_t)e * F_DIM * C_DIM
                     + (size_t)(kh * 1024 + kg * 8) * C_DIM + c0 + bcol;

  f32x4 acc[4][4] = {};
  int wr = (wid >> 1) * 64, wc = (wid & 1) * 64;
  int fr = lane & 15, fq = lane >> 4;

  float rb[8];
#pragma unroll
  for (int j = 0; j < 8; ++j) rb[j] = w2p[(size_t)j * C_DIM];
  glds16(asrc[0], &A_lds[0][wid * 512]);
  glds16(asrc[1], &A_lds[0][(8 + wid) * 512]);

#pragma unroll 2
  for (int tt = 0; tt < 32; ++tt) {
    int cur = tt & 1;
    {
      union { f16x8 v; f16x2 h[4]; } u;
      u.h[0] = pkrtz(rb[0], rb[1]); u.h[1] = pkrtz(rb[2], rb[3]);
      u.h[2] = pkrtz(rb[4], rb[5]); u.h[3] = pkrtz(rb[6], rb[7]);
      *(f16x8*)&B_lds[cur][bso] = u.v;
    }
    __syncthreads();
    int knext = ((tt + 1) & 31) * 32;
    glds16(asrc[0] + knext, &A_lds[cur ^ 1][wid * 512]);
    glds16(asrc[1] + knext, &A_lds[cur ^ 1][(8 + wid) * 512]);
#pragma unroll
    for (int j = 0; j < 8; ++j) rb[j] = w2p[(size_t)(knext + j) * C_DIM];
    f16x8 a[4];
#pragma unroll
    for (int m = 0; m < 4; ++m) {
      int row = wr + m * 16 + fr;
      a[m] = *(const f16x8*)&A_lds[cur][row * 32 + (fq ^ ((row >> 1) & 3)) * 8];
    }
    f16x8 b[4];
#pragma unroll
    for (int n = 0; n < 4; ++n) {
      int col = wc + n * 16 + fr;
      b[n] = *(const f16x8*)&B_lds[cur][col * 32 + (fq ^ ((col >> 1) & 3)) * 8];
    }
#pragma unroll
    for (int m = 0; m < 4; ++m)
#pragma unroll
      for (int n = 0; n < 4; ++n)
        acc[m][n] = __builtin_amdgcn_mfma_f32_16x16x32_f16(a[m], b[n], acc[m][n], 0, 0, 0);
  }

#pragma unroll
  for (int m = 0; m < 4; ++m)
#pragma unroll
    for (int n = 0; n < 4; ++n)
#pragma unroll
      for (int i = 0; i < 4; ++i) {
        int lr = row0 + wr + m * 16 + fq * 4 + i;
        if (lr < cnt)
          yb[(size_t)(off + lr) * C_DIM + c0 + wc + n * 16 + fr] = (f16)acc[m][n][i];
      }
}

// ---------------- combine ----------------
__global__ void combine_kernel(const f16* __restrict__ y0, const f16* __restrict__ y1,
                               const int* __restrict__ slot_of,
                               const float* __restrict__ topw,
                               float* __restrict__ out) {
  int n = blockIdx.x;
  int s0 = slot_of[2 * n], s1 = slot_of[2 * n + 1];
  float g0 = topw[2 * n], g1 = topw[2 * n + 1];
  int c = threadIdx.x * 4;
  f16x4 a0 = *(const f16x4*)(y0 + (size_t)s0 * C_DIM + c);
  f16x4 a1 = *(const f16x4*)(y1 + (size_t)s0 * C_DIM + c);
  f16x4 b0 = *(const f16x4*)(y0 + (size_t)s1 * C_DIM + c);
  f16x4 b1 = *(const f16x4*)(y1 + (size_t)s1 * C_DIM + c);
  f32x4 o;
#pragma unroll
  for (int i = 0; i < 4; ++i)
    o[i] = g0 * ((float)a0[i] + (float)a1[i]) + g1 * ((float)b0[i] + (float)b1[i]);
  *(f32x4*)(out + (size_t)n * C_DIM + c) = o;
}

extern "C" void kernel_launch(void* const* d_in, const int* in_sizes, int n_in,
                              void* d_out, int out_size, void* d_ws, size_t ws_size,
                              hipStream_t stream) {
  const float* x  = (const float*)d_in[0];
  const float* Wr = (const float*)d_in[1];
  const float* w1 = (const float*)d_in[2];
  const float* w3 = (const float*)d_in[3];
  const float* w2 = (const float*)d_in[4];
  float* out = (float*)d_out;
  char* ws = (char*)d_ws;

  int* counts    = (int*)(ws + WS_COUNTS);
  int* offsets   = (int*)(ws + WS_OFFSETS);
  int* tilestart = (int*)(ws + WS_TILESTART);
  int* cursor    = (int*)(ws + WS_CURSOR);
  int* topi      = (int*)(ws + WS_TOPI);
  float* topw    = (float*)(ws + WS_TOPW);
  int* rows_perm = (int*)(ws + WS_ROWS);
  int* slot_of   = (int*)(ws + WS_SLOT);
  f16* x16       = (f16*)(ws + WS_X16);
  f16* h_buf     = (f16*)(ws + WS_H);
  f16* y0        = (f16*)(ws + WS_Y0);
  f16* y1        = (f16*)(ws + WS_Y1);

  (void)hipMemsetAsync(ws, 0, 256, stream);
  cvtx_kernel<<<N_TOK * C_DIM / 8 / 256, 256, 0, stream>>>(x, x16);
  router_kernel<<<N_TOK / 4, 256, 0, stream>>>(x, Wr, counts, topi, topw);
  scan_kernel<<<1, 64, 0, stream>>>(counts, offsets, tilestart, cursor);
  scatter_kernel<<<N_TOK / 256, 256, 0, stream>>>(topi, cursor, rows_perm, slot_of);
  upproj_kernel<<<dim3(F_DIM / 128, MAXT2), 512, 0, stream>>>(
      x16, w1, w3, counts, offsets, tilestart, rows_perm, h_buf);
  downproj_kernel<<<dim3(C_DIM / 128, MAXT2, 2), 512, 0, stream>>>(
      h_buf, w2, counts, offsets, tilestart, y0, y1);
  combine_kernel<<<N_TOK, 256, 0, stream>>>(y0, y1, slot_of, topw, out);
}